// Round 6
// baseline (108.684 us; speedup 1.0000x reference)
//
#include <hip/hip_runtime.h>
#include <hip/hip_bf16.h>

typedef __bf16 bf16x8 __attribute__((ext_vector_type(8)));
typedef __bf16 bf16x4 __attribute__((ext_vector_type(4)));
typedef float  f32x4  __attribute__((ext_vector_type(4)));

#define Bsz 64
#define Tdim 2048
#define Edim 512
#define Ddim 1024
#define Udim 128
#define CHUNK 256
#define NCHUNK 8           // Tdim / CHUNK

__device__ inline bf16x4 cvt4(float4 v) {   // compiler emits v_cvt_pk_bf16_f32 pairs
    bf16x4 h;
    h[0] = (__bf16)v.x; h[1] = (__bf16)v.y; h[2] = (__bf16)v.z; h[3] = (__bf16)v.w;
    return h;
}

__device__ inline float fast_tanh(float x) {
    float e = __expf(2.f * x);                 // inf for large x -> 1; 0 for very neg -> -1
    return 1.f - __fdividef(2.f, e + 1.f);
}

// ---- K_prep: blocks [0,256): qb (8 jobs/wave); [256,272): Wk->bf16 (4 iters) ----
__global__ __launch_bounds__(256) void k_prep(const float* __restrict__ q,
                                              const float* __restrict__ Wq,
                                              const float* __restrict__ bparam,
                                              const float* __restrict__ convb,
                                              const float* __restrict__ Wk,
                                              unsigned short* __restrict__ wkbf,
                                              float* __restrict__ qb) {
    int bid = blockIdx.x, tid = threadIdx.x;
    if (bid >= 256) {
        int cb = bid - 256;
        #pragma unroll
        for (int k = 0; k < 4; ++k) {
            int i = (((cb * 4 + k) * 256) + tid) * 4;
            float4 v = *reinterpret_cast<const float4*>(Wk + i);
            *reinterpret_cast<bf16x4*>(wkbf + i) = cvt4(v);
        }
        return;
    }
    int wg   = bid * 4 + (tid >> 6);          // [0,1024)
    int lane = tid & 63;
    int b  = wg >> 4;                          // 16 waves per b
    int u0 = (wg & 15) * 8;                    // 8 consecutive u per wave
    const float* qr = q + (size_t)b * Ddim + lane * 16;
    float4 qv[4];
    #pragma unroll
    for (int i = 0; i < 4; ++i) qv[i] = *reinterpret_cast<const float4*>(qr + i * 4);
    float s[8];
    #pragma unroll
    for (int jj = 0; jj < 8; ++jj) {
        const float* wr = Wq + (size_t)(u0 + jj) * Ddim + lane * 16;
        float acc = 0.f;
        #pragma unroll
        for (int i = 0; i < 4; ++i) {
            float4 w = *reinterpret_cast<const float4*>(wr + i * 4);
            acc += qv[i].x * w.x + qv[i].y * w.y + qv[i].z * w.z + qv[i].w * w.w;
        }
        s[jj] = acc;
    }
    #pragma unroll
    for (int m = 32; m; m >>= 1) {
        #pragma unroll
        for (int jj = 0; jj < 8; ++jj) s[jj] += __shfl_xor(s[jj], m);
    }
    if (lane == 0) {
        #pragma unroll
        for (int jj = 0; jj < 8; ++jj)
            qb[b * 128 + u0 + jj] = s[jj] + bparam[u0 + jj] + convb[u0 + jj];
    }
}

// ---- K1: fused score + partial softmax + partial context; chunk=256 rows ----
// 256 thr (4 waves); tile 256 t x 128 u; single-buffered LDS, K-steps of 64 over E
__global__ __launch_bounds__(256) void k_score_ctx(const float* __restrict__ enc,
                                                   const float* __restrict__ prev,
                                                   const unsigned short* __restrict__ wkbf,
                                                   const float* __restrict__ qb,
                                                   const float* __restrict__ conv_w,
                                                   const float* __restrict__ v_w,
                                                   const float* __restrict__ v_b,
                                                   const int* __restrict__ lengths,
                                                   float* __restrict__ score_out,
                                                   float* __restrict__ m_ws,
                                                   float* __restrict__ l_ws,
                                                   float* __restrict__ c_ws) {
    __shared__ alignas(16) unsigned short At[256 * 64];     // 32 KB, swizzled
    __shared__ alignas(16) unsigned short Bt[128 * 64];     // 16 KB, swizzled
    __shared__ float s_prev[258];
    __shared__ float s_qb[128];
    __shared__ float s_vw[128];
    __shared__ float s_cw[3][128];
    __shared__ float s_score[256];
    __shared__ float s_p[256];
    __shared__ alignas(16) float s_cred[128 * 4];

    const int tid   = threadIdx.x;
    const int b     = blockIdx.y;
    const int chunk = blockIdx.x;
    const int t0    = chunk * CHUNK;
    const int lane  = tid & 63, wid = tid >> 6;
    const int len   = lengths[b];
    const int pidx  = b * NCHUNK + chunk;

    if (t0 >= len) {                         // fully-masked chunk: empty partial, exit
        if (tid == 0) { m_ws[pidx] = -3.4e38f; l_ws[pidx] = 0.f; }
        return;
    }

    if (tid < 128) {
        s_qb[tid]    = qb[b * 128 + tid];
        s_vw[tid]    = v_w[tid];
        s_cw[0][tid] = conv_w[tid * 3 + 0];
        s_cw[1][tid] = conv_w[tid * 3 + 1];
        s_cw[2][tid] = conv_w[tid * 3 + 2];
    }
    if (tid < 258 - 128 && tid + 128 < 258) {}   // (no-op; keep simple)
    if (tid < 258) {
        int idx = t0 - 1 + tid;
        s_prev[tid] = (idx >= 0 && idx < Tdim) ? prev[b * Tdim + idx] : 0.f;
    }
    if (tid < 2) {
        int idx = t0 - 1 + 256 + tid;
        s_prev[256 + tid] = (idx >= 0 && idx < Tdim) ? prev[b * Tdim + idx] : 0.f;
    }

    const float* encb = enc + ((size_t)b * Tdim + t0) * Edim;

    f32x4 acc[4][8];
    #pragma unroll
    for (int m2 = 0; m2 < 4; ++m2)
        #pragma unroll
        for (int n = 0; n < 8; ++n) acc[m2][n] = (f32x4){0.f, 0.f, 0.f, 0.f};

    for (int e0 = 0; e0 < Edim; e0 += 64) {
        // stage A: enc[t0..t0+255][e0..e0+63] -> bf16, XOR-swizzled 128B rows
        #pragma unroll
        for (int i = 0; i < 16; ++i) {
            int lin = tid + i * 256;
            int r = lin >> 4, c4 = lin & 15;
            float4 v = *reinterpret_cast<const float4*>(encb + (size_t)r * Edim + e0 + c4 * 4);
            int off = (r * 128 + c4 * 8) ^ ((r & 7) << 4);
            *reinterpret_cast<bf16x4*>(reinterpret_cast<char*>(At) + off) = cvt4(v);
        }
        // stage B: Wk_bf16[0..127][e0..e0+63]
        #pragma unroll
        for (int i = 0; i < 4; ++i) {
            int lin = tid + i * 256;
            int u = lin >> 3, c8 = lin & 7;
            uint4 w = *reinterpret_cast<const uint4*>(wkbf + (size_t)u * Edim + e0 + c8 * 8);
            int off = (u * 128 + c8 * 16) ^ ((u & 7) << 4);
            *reinterpret_cast<uint4*>(reinterpret_cast<char*>(Bt) + off) = w;
        }
        __syncthreads();
        #pragma unroll
        for (int kk = 0; kk < 2; ++kk) {
            #pragma unroll
            for (int m2 = 0; m2 < 4; ++m2) {
                int ar = wid * 64 + m2 * 16 + (lane & 15);
                int abyte = (ar * 128 + kk * 64 + (lane >> 4) * 16) ^ ((ar & 7) << 4);
                bf16x8 af = *reinterpret_cast<const bf16x8*>(reinterpret_cast<const char*>(At) + abyte);
                #pragma unroll
                for (int n = 0; n < 8; ++n) {
                    int br = n * 16 + (lane & 15);
                    int bbyte = (br * 128 + kk * 64 + (lane >> 4) * 16) ^ ((br & 7) << 4);
                    bf16x8 bv = *reinterpret_cast<const bf16x8*>(reinterpret_cast<const char*>(Bt) + bbyte);
                    acc[m2][n] = __builtin_amdgcn_mfma_f32_16x16x32_bf16(af, bv, acc[m2][n], 0, 0, 0);
                }
            }
        }
        __syncthreads();
    }

    // epilogue: score = v·tanh(acc + qb + conv) + v_b
    float sc[4][4];
    #pragma unroll
    for (int m2 = 0; m2 < 4; ++m2)
        #pragma unroll
        for (int j = 0; j < 4; ++j) sc[m2][j] = 0.f;
    #pragma unroll
    for (int m2 = 0; m2 < 4; ++m2) {
        #pragma unroll
        for (int n = 0; n < 8; ++n) {
            int u = n * 16 + (lane & 15);
            float c0 = s_cw[0][u], c1 = s_cw[1][u], c2 = s_cw[2][u];
            float qbu = s_qb[u], vwu = s_vw[u];
            #pragma unroll
            for (int j = 0; j < 4; ++j) {
                int tl = wid * 64 + m2 * 16 + (lane >> 4) * 4 + j;
                float conv = s_prev[tl] * c0 + s_prev[tl + 1] * c1 + s_prev[tl + 2] * c2;
                sc[m2][j] += vwu * fast_tanh(acc[m2][n][j] + qbu + conv);
            }
        }
    }
    #pragma unroll
    for (int m2 = 0; m2 < 4; ++m2)
        #pragma unroll
        for (int j = 0; j < 4; ++j) {
            sc[m2][j] += __shfl_xor(sc[m2][j], 1);
            sc[m2][j] += __shfl_xor(sc[m2][j], 2);
            sc[m2][j] += __shfl_xor(sc[m2][j], 4);
            sc[m2][j] += __shfl_xor(sc[m2][j], 8);
        }
    if ((lane & 15) == 0) {
        float vb = v_b[0];
        #pragma unroll
        for (int m2 = 0; m2 < 4; ++m2) {
            int tl = wid * 64 + m2 * 16 + (lane >> 4) * 4;
            #pragma unroll
            for (int j = 0; j < 4; ++j) {
                float s = sc[m2][j] + vb;
                s_score[tl + j] = s;
                score_out[b * Tdim + t0 + tl + j] = s;   // raw; normalized by combine
            }
        }
    }
    __syncthreads();

    // partial softmax over the chunk's 256 rows (each lane covers rows lane + h*64)
    float sv[4], pv[4];
    float m = -3.4e38f;
    #pragma unroll
    for (int h = 0; h < 4; ++h) {
        sv[h] = (t0 + h * 64 + lane < len) ? s_score[h * 64 + lane] : -3.4e38f;
        m = fmaxf(m, sv[h]);
    }
    #pragma unroll
    for (int s = 32; s; s >>= 1) m = fmaxf(m, __shfl_xor(m, s));
    float l = 0.f;
    #pragma unroll
    for (int h = 0; h < 4; ++h) {
        pv[h] = (t0 + h * 64 + lane < len) ? __expf(sv[h] - m) : 0.f;
        l += pv[h];
    }
    #pragma unroll
    for (int s = 32; s; s >>= 1) l += __shfl_xor(l, s);
    if (tid < 64) {
        #pragma unroll
        for (int h = 0; h < 4; ++h) s_p[h * 64 + tid] = pv[h];
    }
    if (tid == 0) { m_ws[pidx] = m; l_ws[pidx] = l; }
    __syncthreads();

    // partial context: c[e] = sum_t p_t * enc[t,e]   (tile re-read; L2/L3-hot)
    {
        int e4 = (tid & 127) * 4;
        int th = tid >> 7;
        float4 a = make_float4(0.f, 0.f, 0.f, 0.f);
        #pragma unroll 4
        for (int t = th; t < CHUNK; t += 2) {
            float pt = s_p[t];
            float4 v = *reinterpret_cast<const float4*>(encb + (size_t)t * Edim + e4);
            a.x += pt * v.x; a.y += pt * v.y; a.z += pt * v.z; a.w += pt * v.w;
        }
        if (th == 1) *reinterpret_cast<float4*>(&s_cred[(tid & 127) * 4]) = a;
        __syncthreads();
        if (th == 0) {
            float4 o = *reinterpret_cast<const float4*>(&s_cred[tid * 4]);
            a.x += o.x; a.y += o.y; a.z += o.z; a.w += o.w;
            *reinterpret_cast<float4*>(c_ws + (size_t)pidx * Edim + e4) = a;
        }
    }
}

// ---- K2: combine partials -> context + normalized attn ----
__global__ __launch_bounds__(256) void k_combine(const float* __restrict__ m_ws,
                                                 const float* __restrict__ l_ws,
                                                 const float* __restrict__ c_ws,
                                                 const int* __restrict__ lengths,
                                                 float* __restrict__ ctx,
                                                 float* __restrict__ attn) {
    int b = blockIdx.x, tid = threadIdx.x;
    int lane = tid & 63, wid = tid >> 6;
    __shared__ float s_w[NCHUNK];
    __shared__ float sM, sinvL;

    if (wid == 0) {
        float mj = (lane < NCHUNK) ? m_ws[b * NCHUNK + lane] : -3.4e38f;
        float lj = (lane < NCHUNK) ? l_ws[b * NCHUNK + lane] : 0.f;
        float M = mj;
        #pragma unroll
        for (int s = 32; s; s >>= 1) M = fmaxf(M, __shfl_xor(M, s));
        float w = (lj > 0.f) ? __expf(mj - M) : 0.f;
        float L = lj * w;
        #pragma unroll
        for (int s = 32; s; s >>= 1) L += __shfl_xor(L, s);
        if (lane < NCHUNK) s_w[lane] = w;
        if (lane == 0) { sM = M; sinvL = 1.f / L; }
    }
    __syncthreads();
    float M = sM, invL = sinvL;

    // context: each thread owns 2 consecutive e columns
    {
        int e2 = tid * 2;
        float ax = 0.f, ay = 0.f;
        #pragma unroll
        for (int j = 0; j < NCHUNK; ++j) {
            float w = s_w[j];
            if (w != 0.f) {
                float2 v = *reinterpret_cast<const float2*>(c_ws + ((size_t)(b * NCHUNK + j)) * Edim + e2);
                ax += w * v.x; ay += w * v.y;
            }
        }
        float2 r = make_float2(ax * invL, ay * invL);
        *reinterpret_cast<float2*>(ctx + (size_t)b * Edim + e2) = r;
    }

    // attn: normalize raw scores in place (zero past len)
    int len = lengths[b];
    #pragma unroll
    for (int i = 0; i < Tdim / 256; ++i) {
        int t = tid + i * 256;
        float s = attn[(size_t)b * Tdim + t];
        attn[(size_t)b * Tdim + t] = (t < len) ? __expf(s - M) * invL : 0.f;
    }
}

extern "C" void kernel_launch(void* const* d_in, const int* in_sizes, int n_in,
                              void* d_out, int out_size, void* d_ws, size_t ws_size,
                              hipStream_t stream) {
    const float* queries = (const float*)d_in[0];
    const float* prev    = (const float*)d_in[1];
    const float* enc     = (const float*)d_in[2];
    const float* conv_w  = (const float*)d_in[3];
    const float* conv_b  = (const float*)d_in[4];
    const float* Wq      = (const float*)d_in[5];
    const float* Wk      = (const float*)d_in[6];
    const float* v_w     = (const float*)d_in[7];
    const float* v_b     = (const float*)d_in[8];
    const float* bparam  = (const float*)d_in[9];
    const int*   lengths = (const int*)d_in[10];

    float* out  = (float*)d_out;
    float* ctx  = out;                       // B*E = 32768
    float* attn = out + Bsz * Edim;          // B*T = 131072 (raw scores -> normalized in place)

    char* ws = (char*)d_ws;
    unsigned short* wkbf = (unsigned short*)ws;                 // 128 KB
    float* qb   = (float*)(ws + 131072);                        // 32 KB
    float* m_ws = (float*)(ws + 163840);                        // 2 KB
    float* l_ws = (float*)(ws + 172032);                        // 2 KB
    float* c_ws = (float*)(ws + 196608);                        // 1 MB

    k_prep<<<272, 256, 0, stream>>>(queries, Wq, bparam, conv_b, Wk, wkbf, qb);
    k_score_ctx<<<dim3(NCHUNK, Bsz), 256, 0, stream>>>(enc, prev, wkbf, qb, conv_w, v_w, v_b,
                                                       lengths, attn, m_ws, l_ws, c_ws);
    k_combine<<<Bsz, 256, 0, stream>>>(m_ws, l_ws, c_ws, lengths, ctx, attn);
}

// Round 7
// 104.017 us; speedup vs baseline: 1.0449x; 1.0449x over previous
//
#include <hip/hip_runtime.h>
#include <hip/hip_bf16.h>

typedef __bf16 bf16x8 __attribute__((ext_vector_type(8)));
typedef __bf16 bf16x4 __attribute__((ext_vector_type(4)));
typedef float  f32x4  __attribute__((ext_vector_type(4)));

#define Bsz 64
#define Tdim 2048
#define Edim 512
#define Ddim 1024
#define Udim 128
#define CHUNK 128
#define NCHUNK 16          // Tdim / CHUNK

__device__ inline bf16x4 cvt4(float4 v) {   // compiler emits v_cvt_pk_bf16_f32 pairs
    bf16x4 h;
    h[0] = (__bf16)v.x; h[1] = (__bf16)v.y; h[2] = (__bf16)v.z; h[3] = (__bf16)v.w;
    return h;
}
__device__ inline bf16x8 cvt8(float4 a, float4 b) {
    bf16x8 h;
    h[0] = (__bf16)a.x; h[1] = (__bf16)a.y; h[2] = (__bf16)a.z; h[3] = (__bf16)a.w;
    h[4] = (__bf16)b.x; h[5] = (__bf16)b.y; h[6] = (__bf16)b.z; h[7] = (__bf16)b.w;
    return h;
}

__device__ inline float fast_tanh(float x) {
    float e = __expf(2.f * x);                 // inf for large x -> 1; 0 for very neg -> -1
    return 1.f - __fdividef(2.f, e + 1.f);
}

// ---- K_prep: blocks [0,256): qb (8 jobs/wave); [256,272): Wk -> fragment-major bf16 ----
// wkbf layout: entry E in [0,8192), 8 bf16 each: E = ((es*2+kk)*8 + n)*64 + l
//   u = n*16 + (l&15); e = es*64 + kk*32 + (l>>4)*8
__global__ __launch_bounds__(256) void k_prep(const float* __restrict__ q,
                                              const float* __restrict__ Wq,
                                              const float* __restrict__ bparam,
                                              const float* __restrict__ convb,
                                              const float* __restrict__ Wk,
                                              unsigned short* __restrict__ wkbf,
                                              float* __restrict__ qb) {
    int bid = blockIdx.x, tid = threadIdx.x;
    if (bid >= 256) {
        int cb = bid - 256;
        #pragma unroll
        for (int k = 0; k < 2; ++k) {
            int E = (cb * 256 + tid) * 2 + k;          // [0, 8192)
            int l  = E & 63;
            int n  = (E >> 6) & 7;
            int kk = (E >> 9) & 1;
            int es = E >> 10;
            int u  = n * 16 + (l & 15);
            int e  = es * 64 + kk * 32 + (l >> 4) * 8;
            const float* src = Wk + (size_t)u * Edim + e;
            float4 a = *reinterpret_cast<const float4*>(src);
            float4 b = *reinterpret_cast<const float4*>(src + 4);
            *reinterpret_cast<bf16x8*>(wkbf + (size_t)E * 8) = cvt8(a, b);
        }
        return;
    }
    int wg   = bid * 4 + (tid >> 6);          // [0,1024)
    int lane = tid & 63;
    int b  = wg >> 4;                          // 16 waves per b
    int u0 = (wg & 15) * 8;                    // 8 consecutive u per wave
    const float* qr = q + (size_t)b * Ddim + lane * 16;
    float4 qv[4];
    #pragma unroll
    for (int i = 0; i < 4; ++i) qv[i] = *reinterpret_cast<const float4*>(qr + i * 4);
    float s[8];
    #pragma unroll
    for (int jj = 0; jj < 8; ++jj) {
        const float* wr = Wq + (size_t)(u0 + jj) * Ddim + lane * 16;
        float acc = 0.f;
        #pragma unroll
        for (int i = 0; i < 4; ++i) {
            float4 w = *reinterpret_cast<const float4*>(wr + i * 4);
            acc += qv[i].x * w.x + qv[i].y * w.y + qv[i].z * w.z + qv[i].w * w.w;
        }
        s[jj] = acc;
    }
    #pragma unroll
    for (int m = 32; m; m >>= 1) {
        #pragma unroll
        for (int jj = 0; jj < 8; ++jj) s[jj] += __shfl_xor(s[jj], m);
    }
    if (lane == 0) {
        #pragma unroll
        for (int jj = 0; jj < 8; ++jj)
            qb[b * 128 + u0 + jj] = s[jj] + bparam[u0 + jj] + convb[u0 + jj];
    }
}

// ---- K1: fused score + partial softmax + partial context; chunk=128 rows ----
// 256 thr (4 waves); tile 128 t x 128 u; A in LDS (swizzled), B direct from L2 (fragment-major)
__global__ __launch_bounds__(256) void k_score_ctx(const float* __restrict__ enc,
                                                   const float* __restrict__ prev,
                                                   const unsigned short* __restrict__ wkbf,
                                                   const float* __restrict__ qb,
                                                   const float* __restrict__ conv_w,
                                                   const float* __restrict__ v_w,
                                                   const float* __restrict__ v_b,
                                                   const int* __restrict__ lengths,
                                                   float* __restrict__ score_out,
                                                   float* __restrict__ m_ws,
                                                   float* __restrict__ l_ws,
                                                   float* __restrict__ c_ws) {
    __shared__ alignas(16) unsigned short At[128 * 64];     // 16 KB, swizzled
    __shared__ float s_prev[130];
    __shared__ float s_qb[128];
    __shared__ float s_vw[128];
    __shared__ float s_cw[3][128];
    __shared__ float s_score[128];
    __shared__ float s_p[128];
    __shared__ alignas(16) float s_cred[128 * 4];

    const int tid   = threadIdx.x;
    const int b     = blockIdx.y;
    const int chunk = blockIdx.x;
    const int t0    = chunk * CHUNK;
    const int lane  = tid & 63, wid = tid >> 6;
    const int len   = lengths[b];
    const int pidx  = b * NCHUNK + chunk;

    if (t0 >= len) {                         // fully-masked chunk: empty partial, exit
        if (tid == 0) { m_ws[pidx] = -3.4e38f; l_ws[pidx] = 0.f; }
        return;
    }

    if (tid < 128) {
        s_qb[tid]    = qb[b * 128 + tid];
        s_vw[tid]    = v_w[tid];
        s_cw[0][tid] = conv_w[tid * 3 + 0];
        s_cw[1][tid] = conv_w[tid * 3 + 1];
        s_cw[2][tid] = conv_w[tid * 3 + 2];
    }
    if (tid < 130) {
        int idx = t0 - 1 + tid;
        s_prev[tid] = (idx >= 0 && idx < Tdim) ? prev[b * Tdim + idx] : 0.f;
    }

    const float* encb = enc + ((size_t)b * Tdim + t0) * Edim;
    const unsigned short* wb = wkbf + lane * 8;   // fragment-major base for this lane

    f32x4 acc[2][8];
    #pragma unroll
    for (int m2 = 0; m2 < 2; ++m2)
        #pragma unroll
        for (int n = 0; n < 8; ++n) acc[m2][n] = (f32x4){0.f, 0.f, 0.f, 0.f};

    for (int es = 0; es < 8; ++es) {
        const int e0 = es * 64;
        // stage A: enc[t0..t0+127][e0..e0+63] -> bf16, XOR-swizzled 128B rows, 16B writes
        #pragma unroll
        for (int i = 0; i < 4; ++i) {
            int lin = tid + i * 256;
            int r = lin >> 3, c8 = lin & 7;
            const float* src = encb + (size_t)r * Edim + e0 + c8 * 8;
            float4 va = *reinterpret_cast<const float4*>(src);
            float4 vb2 = *reinterpret_cast<const float4*>(src + 4);
            int off = (r * 128 + c8 * 16) ^ ((r & 7) << 4);
            *reinterpret_cast<bf16x8*>(reinterpret_cast<char*>(At) + off) = cvt8(va, vb2);
        }
        __syncthreads();
        #pragma unroll
        for (int kk = 0; kk < 2; ++kk) {
            bf16x8 af[2];
            #pragma unroll
            for (int m2 = 0; m2 < 2; ++m2) {
                int ar = wid * 32 + m2 * 16 + (lane & 15);
                int abyte = (ar * 128 + kk * 64 + (lane >> 4) * 16) ^ ((ar & 7) << 4);
                af[m2] = *reinterpret_cast<const bf16x8*>(reinterpret_cast<const char*>(At) + abyte);
            }
            const unsigned short* wkk = wb + (size_t)((es * 2 + kk) * 8) * 512;
            bf16x8 bv[8];
            #pragma unroll
            for (int n = 0; n < 8; ++n)
                bv[n] = *reinterpret_cast<const bf16x8*>(wkk + (size_t)n * 512);
            #pragma unroll
            for (int n = 0; n < 8; ++n) {
                acc[0][n] = __builtin_amdgcn_mfma_f32_16x16x32_bf16(af[0], bv[n], acc[0][n], 0, 0, 0);
                acc[1][n] = __builtin_amdgcn_mfma_f32_16x16x32_bf16(af[1], bv[n], acc[1][n], 0, 0, 0);
            }
        }
        __syncthreads();
    }

    // epilogue: score = v·tanh(acc + qb + conv) + v_b
    float sc[2][4] = {{0.f,0.f,0.f,0.f},{0.f,0.f,0.f,0.f}};
    #pragma unroll
    for (int m2 = 0; m2 < 2; ++m2) {
        #pragma unroll
        for (int n = 0; n < 8; ++n) {
            int u = n * 16 + (lane & 15);
            float c0 = s_cw[0][u], c1 = s_cw[1][u], c2 = s_cw[2][u];
            float qbu = s_qb[u], vwu = s_vw[u];
            #pragma unroll
            for (int j = 0; j < 4; ++j) {
                int tl = wid * 32 + m2 * 16 + (lane >> 4) * 4 + j;
                float conv = s_prev[tl] * c0 + s_prev[tl + 1] * c1 + s_prev[tl + 2] * c2;
                sc[m2][j] += vwu * fast_tanh(acc[m2][n][j] + qbu + conv);
            }
        }
    }
    #pragma unroll
    for (int m2 = 0; m2 < 2; ++m2)
        #pragma unroll
        for (int j = 0; j < 4; ++j) {
            sc[m2][j] += __shfl_xor(sc[m2][j], 1);
            sc[m2][j] += __shfl_xor(sc[m2][j], 2);
            sc[m2][j] += __shfl_xor(sc[m2][j], 4);
            sc[m2][j] += __shfl_xor(sc[m2][j], 8);
        }
    if ((lane & 15) == 0) {
        float vb = v_b[0];
        #pragma unroll
        for (int m2 = 0; m2 < 2; ++m2) {
            int tl = wid * 32 + m2 * 16 + (lane >> 4) * 4;
            #pragma unroll
            for (int j = 0; j < 4; ++j) {
                float s = sc[m2][j] + vb;
                s_score[tl + j] = s;
                score_out[b * Tdim + t0 + tl + j] = s;   // raw; normalized by combine
            }
        }
    }
    __syncthreads();

    // partial softmax over the chunk's 128 rows (lane covers rows lane, lane+64)
    float sv0 = (t0 + lane < len)      ? s_score[lane]      : -3.4e38f;
    float sv1 = (t0 + 64 + lane < len) ? s_score[lane + 64] : -3.4e38f;
    float m = fmaxf(sv0, sv1);
    #pragma unroll
    for (int s = 32; s; s >>= 1) m = fmaxf(m, __shfl_xor(m, s));
    float p0 = (t0 + lane < len)      ? __expf(sv0 - m) : 0.f;
    float p1 = (t0 + 64 + lane < len) ? __expf(sv1 - m) : 0.f;
    float l = p0 + p1;
    #pragma unroll
    for (int s = 32; s; s >>= 1) l += __shfl_xor(l, s);
    if (tid < 64) { s_p[tid] = p0; s_p[tid + 64] = p1; }
    if (tid == 0) { m_ws[pidx] = m; l_ws[pidx] = l; }
    __syncthreads();

    // partial context: c[e] = sum_t p_t * enc[t,e]   (tile re-read; L2/L3-hot)
    {
        int e4 = (tid & 127) * 4;
        int th = tid >> 7;
        float4 a = make_float4(0.f, 0.f, 0.f, 0.f);
        #pragma unroll 4
        for (int t = th; t < CHUNK; t += 2) {
            float pt = s_p[t];
            float4 v = *reinterpret_cast<const float4*>(encb + (size_t)t * Edim + e4);
            a.x += pt * v.x; a.y += pt * v.y; a.z += pt * v.z; a.w += pt * v.w;
        }
        if (th == 1) *reinterpret_cast<float4*>(&s_cred[(tid & 127) * 4]) = a;
        __syncthreads();
        if (th == 0) {
            float4 o = *reinterpret_cast<const float4*>(&s_cred[tid * 4]);
            a.x += o.x; a.y += o.y; a.z += o.z; a.w += o.w;
            *reinterpret_cast<float4*>(c_ws + (size_t)pidx * Edim + e4) = a;
        }
    }
}

// ---- K2: combine partials -> context + normalized attn ----
__global__ __launch_bounds__(256) void k_combine(const float* __restrict__ m_ws,
                                                 const float* __restrict__ l_ws,
                                                 const float* __restrict__ c_ws,
                                                 const int* __restrict__ lengths,
                                                 float* __restrict__ ctx,
                                                 float* __restrict__ attn) {
    int b = blockIdx.x, tid = threadIdx.x;
    int lane = tid & 63, wid = tid >> 6;
    __shared__ float s_w[NCHUNK];
    __shared__ float sM, sinvL;

    if (wid == 0) {
        float mj = (lane < NCHUNK) ? m_ws[b * NCHUNK + lane] : -3.4e38f;
        float lj = (lane < NCHUNK) ? l_ws[b * NCHUNK + lane] : 0.f;
        float M = mj;
        #pragma unroll
        for (int s = 32; s; s >>= 1) M = fmaxf(M, __shfl_xor(M, s));
        float w = (lj > 0.f) ? __expf(mj - M) : 0.f;
        float L = lj * w;
        #pragma unroll
        for (int s = 32; s; s >>= 1) L += __shfl_xor(L, s);
        if (lane < NCHUNK) s_w[lane] = w;
        if (lane == 0) { sM = M; sinvL = 1.f / L; }
    }
    __syncthreads();
    float M = sM, invL = sinvL;

    // context: each thread owns 2 consecutive e columns
    {
        int e2 = tid * 2;
        float ax = 0.f, ay = 0.f;
        #pragma unroll
        for (int j = 0; j < NCHUNK; ++j) {
            float w = s_w[j];
            if (w != 0.f) {
                float2 v = *reinterpret_cast<const float2*>(c_ws + ((size_t)(b * NCHUNK + j)) * Edim + e2);
                ax += w * v.x; ay += w * v.y;
            }
        }
        float2 r = make_float2(ax * invL, ay * invL);
        *reinterpret_cast<float2*>(ctx + (size_t)b * Edim + e2) = r;
    }

    // attn: normalize raw scores in place (zero past len)
    int len = lengths[b];
    #pragma unroll
    for (int i = 0; i < Tdim / 256; ++i) {
        int t = tid + i * 256;
        float s = attn[(size_t)b * Tdim + t];
        attn[(size_t)b * Tdim + t] = (t < len) ? __expf(s - M) * invL : 0.f;
    }
}

extern "C" void kernel_launch(void* const* d_in, const int* in_sizes, int n_in,
                              void* d_out, int out_size, void* d_ws, size_t ws_size,
                              hipStream_t stream) {
    const float* queries = (const float*)d_in[0];
    const float* prev    = (const float*)d_in[1];
    const float* enc     = (const float*)d_in[2];
    const float* conv_w  = (const float*)d_in[3];
    const float* conv_b  = (const float*)d_in[4];
    const float* Wq      = (const float*)d_in[5];
    const float* Wk      = (const float*)d_in[6];
    const float* v_w     = (const float*)d_in[7];
    const float* v_b     = (const float*)d_in[8];
    const float* bparam  = (const float*)d_in[9];
    const int*   lengths = (const int*)d_in[10];

    float* out  = (float*)d_out;
    float* ctx  = out;                       // B*E = 32768
    float* attn = out + Bsz * Edim;          // B*T = 131072 (raw scores -> normalized in place)

    char* ws = (char*)d_ws;
    unsigned short* wkbf = (unsigned short*)ws;                 // 128 KB (fragment-major)
    float* qb   = (float*)(ws + 131072);                        // 32 KB
    float* m_ws = (float*)(ws + 163840);                        // 4 KB
    float* l_ws = (float*)(ws + 172032);                        // 4 KB
    float* c_ws = (float*)(ws + 196608);                        // 2 MB

    k_prep<<<272, 256, 0, stream>>>(queries, Wq, bparam, conv_b, Wk, wkbf, qb);
    k_score_ctx<<<dim3(NCHUNK, Bsz), 256, 0, stream>>>(enc, prev, wkbf, qb, conv_w, v_w, v_b,
                                                       lengths, attn, m_ws, l_ws, c_ws);
    k_combine<<<Bsz, 256, 0, stream>>>(m_ws, l_ws, c_ws, lengths, ctx, attn);
}

// Round 8
// 81.726 us; speedup vs baseline: 1.3298x; 1.2727x over previous
//
#include <hip/hip_runtime.h>
#include <hip/hip_bf16.h>

typedef __bf16 bf16x8 __attribute__((ext_vector_type(8)));
typedef float  f32x4  __attribute__((ext_vector_type(4)));

#define Bsz 64
#define Tdim 2048
#define Edim 512
#define Ddim 1024
#define Udim 128
#define CHUNK 128
#define NCHUNK 16          // Tdim / CHUNK

__device__ inline bf16x8 cvt8(float4 a, float4 b) {   // -> v_cvt_pk_bf16_f32 x4
    bf16x8 h;
    h[0] = (__bf16)a.x; h[1] = (__bf16)a.y; h[2] = (__bf16)a.z; h[3] = (__bf16)a.w;
    h[4] = (__bf16)b.x; h[5] = (__bf16)b.y; h[6] = (__bf16)b.z; h[7] = (__bf16)b.w;
    return h;
}

__device__ inline float fast_tanh(float x) {
    float e = __expf(2.f * x);                 // inf for large x -> 1; 0 for very neg -> -1
    return 1.f - __fdividef(2.f, e + 1.f);
}

// ---- K_prep: blocks [0,256): qb (8 jobs/wave); [256,272): Wk -> PRE-SWIZZLED bf16 ----
// wkbf layout: 8 es-slices of 16384 B. Within a slice, element (u,c8) [u<128, c8<8, 8 bf16]
// lives at byte ((u*128 + c8*16) ^ ((u&7)<<4)) — i.e. the Bt LDS swizzle pre-applied, so the
// score kernel can stage with LINEAR global_load_lds and read with the swizzled pattern.
__global__ __launch_bounds__(256) void k_prep(const float* __restrict__ q,
                                              const float* __restrict__ Wq,
                                              const float* __restrict__ bparam,
                                              const float* __restrict__ convb,
                                              const float* __restrict__ Wk,
                                              unsigned short* __restrict__ wkbf,
                                              float* __restrict__ qb) {
    int bid = blockIdx.x, tid = threadIdx.x;
    if (bid >= 256) {
        int cb = bid - 256;
        #pragma unroll
        for (int k = 0; k < 2; ++k) {
            int E = (cb * 256 + tid) * 2 + k;          // [0, 8192)
            int c8 = E & 7;
            int u  = (E >> 3) & 127;
            int es = E >> 10;
            const float* src = Wk + (size_t)u * Edim + es * 64 + c8 * 8;
            float4 a = *reinterpret_cast<const float4*>(src);
            float4 b = *reinterpret_cast<const float4*>(src + 4);
            int dst = es * 16384 + ((u * 128 + c8 * 16) ^ ((u & 7) << 4));
            *reinterpret_cast<bf16x8*>(reinterpret_cast<char*>(wkbf) + dst) = cvt8(a, b);
        }
        return;
    }
    int wg   = bid * 4 + (tid >> 6);          // [0,1024)
    int lane = tid & 63;
    int b  = wg >> 4;                          // 16 waves per b
    int u0 = (wg & 15) * 8;                    // 8 consecutive u per wave
    const float* qr = q + (size_t)b * Ddim + lane * 16;
    float4 qv[4];
    #pragma unroll
    for (int i = 0; i < 4; ++i) qv[i] = *reinterpret_cast<const float4*>(qr + i * 4);
    float s[8];
    #pragma unroll
    for (int jj = 0; jj < 8; ++jj) {
        const float* wr = Wq + (size_t)(u0 + jj) * Ddim + lane * 16;
        float acc = 0.f;
        #pragma unroll
        for (int i = 0; i < 4; ++i) {
            float4 w = *reinterpret_cast<const float4*>(wr + i * 4);
            acc += qv[i].x * w.x + qv[i].y * w.y + qv[i].z * w.z + qv[i].w * w.w;
        }
        s[jj] = acc;
    }
    #pragma unroll
    for (int m = 32; m; m >>= 1) {
        #pragma unroll
        for (int jj = 0; jj < 8; ++jj) s[jj] += __shfl_xor(s[jj], m);
    }
    if (lane == 0) {
        #pragma unroll
        for (int jj = 0; jj < 8; ++jj)
            qb[b * 128 + u0 + jj] = s[jj] + bparam[u0 + jj] + convb[u0 + jj];
    }
}

// ---- K1: fused score + partial softmax + partial context; chunk=128 rows ----
// 256 thr (4 waves); tile 128 t x 128 u; A reg-staged+cvt to LDS, B via async global_load_lds
__global__ __launch_bounds__(256) void k_score_ctx(const float* __restrict__ enc,
                                                   const float* __restrict__ prev,
                                                   const unsigned short* __restrict__ wkbf,
                                                   const float* __restrict__ qb,
                                                   const float* __restrict__ conv_w,
                                                   const float* __restrict__ v_w,
                                                   const float* __restrict__ v_b,
                                                   const int* __restrict__ lengths,
                                                   float* __restrict__ score_out,
                                                   float* __restrict__ m_ws,
                                                   float* __restrict__ l_ws,
                                                   float* __restrict__ c_ws) {
    __shared__ alignas(16) unsigned short At[128 * 64];     // 16 KB, swizzled
    __shared__ alignas(16) unsigned short Bt[128 * 64];     // 16 KB, swizzled (via preswz global)
    __shared__ float s_prev[130];
    __shared__ float s_qb[128];
    __shared__ float s_vw[128];
    __shared__ float s_cw[3][128];
    __shared__ float s_score[128];
    __shared__ float s_p[128];
    __shared__ alignas(16) float s_cred[128 * 4];

    const int tid   = threadIdx.x;
    const int b     = blockIdx.y;
    const int chunk = blockIdx.x;
    const int t0    = chunk * CHUNK;
    const int lane  = tid & 63, wid = tid >> 6;
    const int len   = lengths[b];
    const int pidx  = b * NCHUNK + chunk;

    if (t0 >= len) {                         // fully-masked chunk: empty partial, exit
        if (tid == 0) { m_ws[pidx] = -3.4e38f; l_ws[pidx] = 0.f; }
        return;
    }

    if (tid < 128) {
        s_qb[tid]    = qb[b * 128 + tid];
        s_vw[tid]    = v_w[tid];
        s_cw[0][tid] = conv_w[tid * 3 + 0];
        s_cw[1][tid] = conv_w[tid * 3 + 1];
        s_cw[2][tid] = conv_w[tid * 3 + 2];
    }
    if (tid < 130) {
        int idx = t0 - 1 + tid;
        s_prev[tid] = (idx >= 0 && idx < Tdim) ? prev[b * Tdim + idx] : 0.f;
    }

    const float* encb = enc + ((size_t)b * Tdim + t0) * Edim;

    f32x4 acc[2][8];
    #pragma unroll
    for (int m2 = 0; m2 < 2; ++m2)
        #pragma unroll
        for (int n = 0; n < 8; ++n) acc[m2][n] = (f32x4){0.f, 0.f, 0.f, 0.f};

    for (int es = 0; es < 8; ++es) {
        const int e0 = es * 64;
        // stage B: async global->LDS, 16B/lane, linear (source pre-swizzled)
        {
            const char* wsrc = reinterpret_cast<const char*>(wkbf) + es * 16384 + tid * 16;
            char* bdst = reinterpret_cast<char*>(Bt) + tid * 16;
            #pragma unroll
            for (int i = 0; i < 4; ++i) {
                __builtin_amdgcn_global_load_lds(
                    (const __attribute__((address_space(1))) unsigned int*)(wsrc + i * 4096),
                    (__attribute__((address_space(3))) unsigned int*)(bdst + i * 4096),
                    16, 0, 0);
            }
        }
        // stage A: enc[t0..t0+127][e0..e0+63] -> bf16, XOR-swizzled, 16B ds_writes
        #pragma unroll
        for (int i = 0; i < 4; ++i) {
            int lin = tid + i * 256;
            int r = lin >> 3, c8 = lin & 7;
            const float* src = encb + (size_t)r * Edim + e0 + c8 * 8;
            float4 va  = *reinterpret_cast<const float4*>(src);
            float4 vb2 = *reinterpret_cast<const float4*>(src + 4);
            int off = (r * 128 + c8 * 16) ^ ((r & 7) << 4);
            *reinterpret_cast<bf16x8*>(reinterpret_cast<char*>(At) + off) = cvt8(va, vb2);
        }
        __syncthreads();
        #pragma unroll
        for (int kk = 0; kk < 2; ++kk) {
            bf16x8 af[2];
            #pragma unroll
            for (int m2 = 0; m2 < 2; ++m2) {
                int ar = wid * 32 + m2 * 16 + (lane & 15);
                int abyte = (ar * 128 + kk * 64 + (lane >> 4) * 16) ^ ((ar & 7) << 4);
                af[m2] = *reinterpret_cast<const bf16x8*>(reinterpret_cast<const char*>(At) + abyte);
            }
            #pragma unroll
            for (int n = 0; n < 8; ++n) {
                int br = n * 16 + (lane & 15);
                int bbyte = (br * 128 + kk * 64 + (lane >> 4) * 16) ^ ((br & 7) << 4);
                bf16x8 bv = *reinterpret_cast<const bf16x8*>(reinterpret_cast<const char*>(Bt) + bbyte);
                acc[0][n] = __builtin_amdgcn_mfma_f32_16x16x32_bf16(af[0], bv, acc[0][n], 0, 0, 0);
                acc[1][n] = __builtin_amdgcn_mfma_f32_16x16x32_bf16(af[1], bv, acc[1][n], 0, 0, 0);
            }
        }
        __syncthreads();
    }

    // epilogue: score = v·tanh(acc + qb + conv) + v_b
    float sc[2][4] = {{0.f,0.f,0.f,0.f},{0.f,0.f,0.f,0.f}};
    #pragma unroll
    for (int m2 = 0; m2 < 2; ++m2) {
        #pragma unroll
        for (int n = 0; n < 8; ++n) {
            int u = n * 16 + (lane & 15);
            float c0 = s_cw[0][u], c1 = s_cw[1][u], c2 = s_cw[2][u];
            float qbu = s_qb[u], vwu = s_vw[u];
            #pragma unroll
            for (int j = 0; j < 4; ++j) {
                int tl = wid * 32 + m2 * 16 + (lane >> 4) * 4 + j;
                float conv = s_prev[tl] * c0 + s_prev[tl + 1] * c1 + s_prev[tl + 2] * c2;
                sc[m2][j] += vwu * fast_tanh(acc[m2][n][j] + qbu + conv);
            }
        }
    }
    #pragma unroll
    for (int m2 = 0; m2 < 2; ++m2)
        #pragma unroll
        for (int j = 0; j < 4; ++j) {
            sc[m2][j] += __shfl_xor(sc[m2][j], 1);
            sc[m2][j] += __shfl_xor(sc[m2][j], 2);
            sc[m2][j] += __shfl_xor(sc[m2][j], 4);
            sc[m2][j] += __shfl_xor(sc[m2][j], 8);
        }
    if ((lane & 15) == 0) {
        float vb = v_b[0];
        #pragma unroll
        for (int m2 = 0; m2 < 2; ++m2) {
            int tl = wid * 32 + m2 * 16 + (lane >> 4) * 4;
            #pragma unroll
            for (int j = 0; j < 4; ++j) {
                float s = sc[m2][j] + vb;
                s_score[tl + j] = s;
                score_out[b * Tdim + t0 + tl + j] = s;   // raw; normalized by combine
            }
        }
    }
    __syncthreads();

    // partial softmax over the chunk's 128 rows (lane covers rows lane, lane+64)
    float sv0 = (t0 + lane < len)      ? s_score[lane]      : -3.4e38f;
    float sv1 = (t0 + 64 + lane < len) ? s_score[lane + 64] : -3.4e38f;
    float m = fmaxf(sv0, sv1);
    #pragma unroll
    for (int s = 32; s; s >>= 1) m = fmaxf(m, __shfl_xor(m, s));
    float p0 = (t0 + lane < len)      ? __expf(sv0 - m) : 0.f;
    float p1 = (t0 + 64 + lane < len) ? __expf(sv1 - m) : 0.f;
    float l = p0 + p1;
    #pragma unroll
    for (int s = 32; s; s >>= 1) l += __shfl_xor(l, s);
    if (tid < 64) { s_p[tid] = p0; s_p[tid + 64] = p1; }
    if (tid == 0) { m_ws[pidx] = m; l_ws[pidx] = l; }
    __syncthreads();

    // partial context: c[e] = sum_t p_t * enc[t,e]   (tile re-read; L2/L3-hot)
    {
        int e4 = (tid & 127) * 4;
        int th = tid >> 7;
        float4 a = make_float4(0.f, 0.f, 0.f, 0.f);
        #pragma unroll 4
        for (int t = th; t < CHUNK; t += 2) {
            float pt = s_p[t];
            float4 v = *reinterpret_cast<const float4*>(encb + (size_t)t * Edim + e4);
            a.x += pt * v.x; a.y += pt * v.y; a.z += pt * v.z; a.w += pt * v.w;
        }
        if (th == 1) *reinterpret_cast<float4*>(&s_cred[(tid & 127) * 4]) = a;
        __syncthreads();
        if (th == 0) {
            float4 o = *reinterpret_cast<const float4*>(&s_cred[tid * 4]);
            a.x += o.x; a.y += o.y; a.z += o.z; a.w += o.w;
            *reinterpret_cast<float4*>(c_ws + (size_t)pidx * Edim + e4) = a;
        }
    }
}

// ---- K2: combine partials -> context + normalized attn ----
__global__ __launch_bounds__(256) void k_combine(const float* __restrict__ m_ws,
                                                 const float* __restrict__ l_ws,
                                                 const float* __restrict__ c_ws,
                                                 const int* __restrict__ lengths,
                                                 float* __restrict__ ctx,
                                                 float* __restrict__ attn) {
    int b = blockIdx.x, tid = threadIdx.x;
    int lane = tid & 63, wid = tid >> 6;
    __shared__ float s_w[NCHUNK];
    __shared__ float sM, sinvL;

    if (wid == 0) {
        float mj = (lane < NCHUNK) ? m_ws[b * NCHUNK + lane] : -3.4e38f;
        float lj = (lane < NCHUNK) ? l_ws[b * NCHUNK + lane] : 0.f;
        float M = mj;
        #pragma unroll
        for (int s = 32; s; s >>= 1) M = fmaxf(M, __shfl_xor(M, s));
        float w = (lj > 0.f) ? __expf(mj - M) : 0.f;
        float L = lj * w;
        #pragma unroll
        for (int s = 32; s; s >>= 1) L += __shfl_xor(L, s);
        if (lane < NCHUNK) s_w[lane] = w;
        if (lane == 0) { sM = M; sinvL = 1.f / L; }
    }
    __syncthreads();
    float M = sM, invL = sinvL;

    // context: each thread owns 2 consecutive e columns
    {
        int e2 = tid * 2;
        float ax = 0.f, ay = 0.f;
        #pragma unroll
        for (int j = 0; j < NCHUNK; ++j) {
            float w = s_w[j];
            if (w != 0.f) {
                float2 v = *reinterpret_cast<const float2*>(c_ws + ((size_t)(b * NCHUNK + j)) * Edim + e2);
                ax += w * v.x; ay += w * v.y;
            }
        }
        float2 r = make_float2(ax * invL, ay * invL);
        *reinterpret_cast<float2*>(ctx + (size_t)b * Edim + e2) = r;
    }

    // attn: normalize raw scores in place (zero past len)
    int len = lengths[b];
    #pragma unroll
    for (int i = 0; i < Tdim / 256; ++i) {
        int t = tid + i * 256;
        float s = attn[(size_t)b * Tdim + t];
        attn[(size_t)b * Tdim + t] = (t < len) ? __expf(s - M) * invL : 0.f;
    }
}

extern "C" void kernel_launch(void* const* d_in, const int* in_sizes, int n_in,
                              void* d_out, int out_size, void* d_ws, size_t ws_size,
                              hipStream_t stream) {
    const float* queries = (const float*)d_in[0];
    const float* prev    = (const float*)d_in[1];
    const float* enc     = (const float*)d_in[2];
    const float* conv_w  = (const float*)d_in[3];
    const float* conv_b  = (const float*)d_in[4];
    const float* Wq      = (const float*)d_in[5];
    const float* Wk      = (const float*)d_in[6];
    const float* v_w     = (const float*)d_in[7];
    const float* v_b     = (const float*)d_in[8];
    const float* bparam  = (const float*)d_in[9];
    const int*   lengths = (const int*)d_in[10];

    float* out  = (float*)d_out;
    float* ctx  = out;                       // B*E = 32768
    float* attn = out + Bsz * Edim;          // B*T = 131072 (raw scores -> normalized in place)

    char* ws = (char*)d_ws;
    unsigned short* wkbf = (unsigned short*)ws;                 // 128 KB (pre-swizzled)
    float* qb   = (float*)(ws + 131072);                        // 32 KB
    float* m_ws = (float*)(ws + 163840);                        // 4 KB
    float* l_ws = (float*)(ws + 172032);                        // 4 KB
    float* c_ws = (float*)(ws + 196608);                        // 2 MB

    k_prep<<<272, 256, 0, stream>>>(queries, Wq, bparam, conv_b, Wk, wkbf, qb);
    k_score_ctx<<<dim3(NCHUNK, Bsz), 256, 0, stream>>>(enc, prev, wkbf, qb, conv_w, v_w, v_b,
                                                       lengths, attn, m_ws, l_ws, c_ws);
    k_combine<<<Bsz, 256, 0, stream>>>(m_ws, l_ws, c_ws, lengths, ctx, attn);
}